// Round 11
// baseline (533.752 us; speedup 1.0000x reference)
//
#include <hip/hip_runtime.h>
#include <hip/hip_fp16.h>

// GraphConv: out = segment_sum(w * X[src] -> dst) @ W + b
// = gather of w * (X@W)[src] per dst (matmul distributes over segment-sum).
// Round 11: r9 structure (best verified, 144us) with ONE change: gather's
// counting sort replaced by a flat record loop + LDS fp32-atomic tile
// (ds_add_f32 is fire-and-forget: no dependency chain, no sort, no scans,
// perfect load balance). r10's segment layout reverted (traffic inflation).
//
// V=100000, E=1250000, C=64, fp32 in/out.

constexpr int V = 100000;
constexpr int E = 1250000;
constexpr int C = 64;

constexpr int NBKT = 1024;        // dst buckets
constexpr int VB   = 98;          // vertices per bucket (1024*98 >= V)
constexpr int BCAP = 1536;        // records per bucket (mean 1221, +9 sigma)
constexpr int FL   = 8;           // LDS staging slots per bucket in bin_kernel
constexpr int OVF_CAP = 16384;

// ---------------- workspace layout (bytes) ----------------
constexpr size_t Y_OFF    = 0;           // V*C*2 = 12,800,000 (fp16)
constexpr size_t BIN_OFF  = 12800000;    // NBKT*BCAP*8 = 12,582,912
constexpr size_t GCNT_OFF = 25382912;    // NBKT*4 = 4,096
constexpr size_t OC_OFF   = 25387008;    // 16
constexpr size_t OVF_OFF  = 25387024;    // OVF_CAP*16 = 262,144
constexpr size_t WS_NEW   = 25649168;

using bf16x8 = __attribute__((ext_vector_type(8))) short;
using f32x4  = __attribute__((ext_vector_type(4))) float;

__device__ __forceinline__ short f2bf(float x) {          // RNE float->bf16 bits
    unsigned u = __float_as_uint(x);
    unsigned r = u + 0x7fffu + ((u >> 16) & 1u);
    return (short)(r >> 16);
}
__device__ __forceinline__ float bf2f(short h) {
    return __uint_as_float(((unsigned)(unsigned short)h) << 16);
}

// ---------------------------------------------------------------------------
// Fused: block 0 zeroes gcnt+oc; blocks [1,1+NBM) compute Y=X@W via MFMA.
// Per wave: one 16-row chunk; 3-term bf16 split (hi*hi + lo*hi + hi*lo).
// Y written fp16.  (Math verified rounds 4-10: absmax 0.0625.)
// ---------------------------------------------------------------------------
constexpr int ZB  = 1;
constexpr int NBM = 1563;                // 6252 waves >= 6250 chunks: 1 chunk/wave

__global__ __launch_bounds__(256) void zero_xw_kernel(const float* __restrict__ X,
                                                      const float* __restrict__ W,
                                                      __half* __restrict__ Y,
                                                      int* __restrict__ gcnt,
                                                      int* __restrict__ oc) {
    if (blockIdx.x < ZB) {
        int i = threadIdx.x;
        #pragma unroll
        for (int j = 0; j < NBKT / 256; ++j) gcnt[i + j * 256] = 0;
        if (i == 0) *oc = 0;
        return;
    }
    __shared__ short Whi[64 * 72];       // Wt[c][k], stride 72
    __shared__ short Wlo[64 * 72];
    for (int idx = threadIdx.x; idx < 4096; idx += 256) {
        int k = idx >> 6, c = idx & 63;
        float w  = W[idx];
        short hi = f2bf(w);
        short lo = f2bf(w - bf2f(hi));
        Whi[c * 72 + k] = hi;
        Wlo[c * 72 + k] = lo;
    }
    __syncthreads();

    const int wave = threadIdx.x >> 6;
    const int lane = threadIdx.x & 63;
    const int m = lane & 15;
    const int q = lane >> 4;

    bf16x8 bhi[4][2], blo[4][2];
    #pragma unroll
    for (int t = 0; t < 4; ++t)
        #pragma unroll
        for (int h = 0; h < 2; ++h) {
            int o = (t * 16 + m) * 72 + h * 32 + q * 8;
            bhi[t][h] = *(const bf16x8*)&Whi[o];
            blo[t][h] = *(const bf16x8*)&Wlo[o];
        }

    const int chunk = (blockIdx.x - ZB) * 4 + wave;
    if (chunk >= V / 16) return;
    {
        const float* xp = X + (chunk * 16 + m) * 64 + q * 8;
        bf16x8 ahi[2], alo[2];
        #pragma unroll
        for (int h = 0; h < 2; ++h) {
            float4 f0 = *(const float4*)(xp + h * 32);
            float4 f1 = *(const float4*)(xp + h * 32 + 4);
            float f[8] = {f0.x, f0.y, f0.z, f0.w, f1.x, f1.y, f1.z, f1.w};
            #pragma unroll
            for (int j = 0; j < 8; ++j) {
                short hi = f2bf(f[j]);
                ahi[h][j] = hi;
                alo[h][j] = f2bf(f[j] - bf2f(hi));
            }
        }
        #pragma unroll
        for (int t = 0; t < 4; ++t) {
            f32x4 acc = {0.f, 0.f, 0.f, 0.f};
            #pragma unroll
            for (int h = 0; h < 2; ++h) {
                acc = __builtin_amdgcn_mfma_f32_16x16x32_bf16(ahi[h], bhi[t][h], acc, 0, 0, 0);
                acc = __builtin_amdgcn_mfma_f32_16x16x32_bf16(alo[h], bhi[t][h], acc, 0, 0, 0);
                acc = __builtin_amdgcn_mfma_f32_16x16x32_bf16(ahi[h], blo[t][h], acc, 0, 0, 0);
            }
            #pragma unroll
            for (int i = 0; i < 4; ++i) {
                int row = chunk * 16 + q * 4 + i;
                Y[row * 64 + t * 16 + m] = __float2half(acc[i]);
            }
        }
    }
}

// ---------------------------------------------------------------------------
// Bin (r9 verified): 512 blocks x 1024 threads, LDS staging + burst flush
// via global cursor.  Record = (local_dst<<17 | src, w_bits).
// ---------------------------------------------------------------------------
constexpr int BIN_BLOCKS = 512;
constexpr int BIN_T      = 1024;

__global__ __launch_bounds__(BIN_T) void bin_kernel(const int*   __restrict__ esrc,
                                                    const int*   __restrict__ edst,
                                                    const float* __restrict__ ew,
                                                    int*  __restrict__ gcnt,
                                                    int2* __restrict__ binned,
                                                    int*  __restrict__ oc,
                                                    int4* __restrict__ ovf) {
    __shared__ int2 stage[NBKT][FL];     // 64 KB
    __shared__ int  lcnt[NBKT];          // 4 KB
    for (int i = threadIdx.x; i < NBKT; i += BIN_T) lcnt[i] = 0;
    __syncthreads();

    const int iters = (E + BIN_BLOCKS * BIN_T - 1) / (BIN_BLOCKS * BIN_T);   // 3
    for (int it = 0; it < iters; ++it) {
        int e = (it * BIN_BLOCKS + blockIdx.x) * BIN_T + threadIdx.x;
        if (e < E) {
            int d = edst[e];
            int s = esrc[e];
            float w = ew[e];
            int bkt = d / VB;
            int ld  = d - bkt * VB;
            int2 rec = make_int2((ld << 17) | s, __float_as_int(w));
            int pos = atomicAdd(&lcnt[bkt], 1);
            if (pos < FL) {
                stage[bkt][pos] = rec;
            } else {                                  // staging spill (~0.1%)
                int g = atomicAdd(&gcnt[bkt], 1);
                if (g < BCAP) binned[bkt * BCAP + g] = rec;
                else { int p = atomicAdd(oc, 1);
                       if (p < OVF_CAP) ovf[p] = make_int4(s, d, __float_as_int(w), 0); }
            }
        }
    }
    __syncthreads();
    // final flush: one thread per bucket — contiguous burst each
    for (int b = threadIdx.x; b < NBKT; b += BIN_T) {
        int n = lcnt[b]; n = n < FL ? n : FL;
        if (n > 0) {
            int g = atomicAdd(&gcnt[b], n);
            for (int i = 0; i < n; ++i) {
                int gi = g + i;
                int2 r = stage[b][i];
                if (gi < BCAP) binned[b * BCAP + gi] = r;
                else { int s = r.x & 0x1FFFF; int ld = r.x >> 17;
                       int p = atomicAdd(oc, 1);
                       if (p < OVF_CAP) ovf[p] = make_int4(s, b * VB + ld, r.y, 0); }
            }
        }
    }
}

// ---------------------------------------------------------------------------
// Bucket gather, flat-atomic version: one 512-thread block per bucket
// (raw 12KB + tile 25KB = 37.4KB LDS -> 4 blocks/CU, 32 waves/CU).
// Zero tile -> stage records coalesced -> flat loop: each wave takes 8
// consecutive records, loads 8 independent Y rows, fire-and-forget
// ds_add_f32 into tile (2 lanes/bank: conflict-free).  No sort, no scans,
// no per-vertex imbalance.  Epilogue: tile + bias -> out (coalesced).
// ---------------------------------------------------------------------------
__global__ __launch_bounds__(512) void bucket_gather_kernel(const int*  __restrict__ gcnt,
                                                            const int2* __restrict__ binned,
                                                            const int*  __restrict__ oc,
                                                            const int4* __restrict__ ovf,
                                                            const __half* __restrict__ Y,
                                                            const float* __restrict__ bias,
                                                            float* __restrict__ out) {
    __shared__ int2  raw[BCAP];          // 12,288 B
    __shared__ float tile[VB * C];       // 25,088 B

    const int tid  = threadIdx.x;
    const int b    = blockIdx.x;
    const int lane = tid & 63;
    const int wv   = tid >> 6;           // 0..7
    const int lo   = b * VB;

    int n = gcnt[b]; n = n < BCAP ? n : BCAP;

    // zero tile (1568 float4) + stage records (coalesced int2 reads)
    float4 z = {0.f, 0.f, 0.f, 0.f};
    for (int i = tid; i < VB * C / 4; i += 512) ((float4*)tile)[i] = z;
    const int2* src = binned + b * BCAP;
    for (int i = tid; i < n; i += 512) raw[i] = src[i];
    __syncthreads();

    // flat record loop: wave wv owns records [k*512 + wv*8, +8)
    for (int base = wv * 8; base < n; base += 64) {
        int m = n - base; m = m < 8 ? m : 8;
        if (m == 8) {
            int2 r0 = raw[base + 0], r1 = raw[base + 1];
            int2 r2 = raw[base + 2], r3 = raw[base + 3];
            int2 r4 = raw[base + 4], r5 = raw[base + 5];
            int2 r6 = raw[base + 6], r7 = raw[base + 7];
            float y0 = __half2float(Y[(r0.x & 0x1FFFF) * C + lane]);
            float y1 = __half2float(Y[(r1.x & 0x1FFFF) * C + lane]);
            float y2 = __half2float(Y[(r2.x & 0x1FFFF) * C + lane]);
            float y3 = __half2float(Y[(r3.x & 0x1FFFF) * C + lane]);
            float y4 = __half2float(Y[(r4.x & 0x1FFFF) * C + lane]);
            float y5 = __half2float(Y[(r5.x & 0x1FFFF) * C + lane]);
            float y6 = __half2float(Y[(r6.x & 0x1FFFF) * C + lane]);
            float y7 = __half2float(Y[(r7.x & 0x1FFFF) * C + lane]);
            atomicAdd(&tile[(r0.x >> 17) * C + lane], __int_as_float(r0.y) * y0);
            atomicAdd(&tile[(r1.x >> 17) * C + lane], __int_as_float(r1.y) * y1);
            atomicAdd(&tile[(r2.x >> 17) * C + lane], __int_as_float(r2.y) * y2);
            atomicAdd(&tile[(r3.x >> 17) * C + lane], __int_as_float(r3.y) * y3);
            atomicAdd(&tile[(r4.x >> 17) * C + lane], __int_as_float(r4.y) * y4);
            atomicAdd(&tile[(r5.x >> 17) * C + lane], __int_as_float(r5.y) * y5);
            atomicAdd(&tile[(r6.x >> 17) * C + lane], __int_as_float(r6.y) * y6);
            atomicAdd(&tile[(r7.x >> 17) * C + lane], __int_as_float(r7.y) * y7);
        } else {
            for (int j = 0; j < m; ++j) {
                int2 r = raw[base + j];
                float yv = __half2float(Y[(r.x & 0x1FFFF) * C + lane]);
                atomicAdd(&tile[(r.x >> 17) * C + lane], __int_as_float(r.y) * yv);
            }
        }
    }

    // overflow backstop (expected 0 records)
    int ovn = *oc; ovn = ovn < OVF_CAP ? ovn : OVF_CAP;
    for (int k = wv; k < ovn; k += 8) {
        int4 r = ovf[k];
        int ld = r.y - lo;
        if (ld >= 0 && ld < VB) {
            float yv = __half2float(Y[r.x * C + lane]);
            atomicAdd(&tile[ld * C + lane], __int_as_float(r.z) * yv);
        }
    }
    __syncthreads();

    // epilogue: tile + bias -> out (coalesced; i&63 == lane since 512%64==0)
    float bias_l = bias[lane];
    for (int i = tid; i < VB * C; i += 512) {
        int v = lo + (i >> 6);
        if (v < V) out[v * C + lane] = tile[i] + bias_l;
    }
}

// ===========================================================================
// Fallback (ws too small): fp32 Y + bias init + fp32 atomic scatter
// ===========================================================================
__global__ __launch_bounds__(256) void xw_kernel(const float* __restrict__ X,
                                                 const float* __restrict__ W,
                                                 float* __restrict__ Y) {
    __shared__ float Ws[64][64];
    const float4* W4 = (const float4*)W;
    float4* Ws4 = (float4*)&Ws[0][0];
    #pragma unroll
    for (int i = 0; i < 4; ++i)
        Ws4[threadIdx.x + 256 * i] = W4[threadIdx.x + 256 * i];
    __syncthreads();
    const int wave = threadIdx.x >> 6;
    const int lane = threadIdx.x & 63;
    for (int row = blockIdx.x * 4 + wave; row < V; row += gridDim.x * 4) {
        float xv = X[row * C + lane];
        float acc = 0.f;
        #pragma unroll
        for (int k = 0; k < C; ++k)
            acc += __shfl(xv, k, 64) * Ws[k][lane];
        Y[row * C + lane] = acc;
    }
}

__global__ __launch_bounds__(256) void init_out_kernel(const float* __restrict__ b,
                                                       float4* __restrict__ out4) {
    int tid = blockIdx.x * 256 + threadIdx.x;
    const int n4 = V * (C / 4);
    if (tid < n4) {
        const float4* b4 = (const float4*)b;
        out4[tid] = b4[tid & 15];
    }
}

__global__ __launch_bounds__(256) void scatter_kernel(const int*   __restrict__ esrc,
                                                      const int*   __restrict__ edst,
                                                      const float* __restrict__ ew,
                                                      const float* __restrict__ Y,
                                                      float*       __restrict__ out) {
    unsigned tid = blockIdx.x * 256u + threadIdx.x;
    unsigned e = tid >> 4;
    if (e >= (unsigned)E) return;
    int g = (tid & 15) * 4;
    int   s  = esrc[e];
    int   d  = edst[e];
    float we = ew[e];
    float4 y = *(const float4*)(Y + s * C + g);
    float* o = out + (size_t)d * C + g;
    atomicAdd(o + 0, we * y.x);
    atomicAdd(o + 1, we * y.y);
    atomicAdd(o + 2, we * y.z);
    atomicAdd(o + 3, we * y.w);
}

extern "C" void kernel_launch(void* const* d_in, const int* in_sizes, int n_in,
                              void* d_out, int out_size, void* d_ws, size_t ws_size,
                              hipStream_t stream) {
    const float* X    = (const float*)d_in[0];
    const int*   esrc = (const int*)  d_in[1];
    const int*   edst = (const int*)  d_in[2];
    const float* ew   = (const float*)d_in[3];
    const float* W    = (const float*)d_in[4];
    const float* b    = (const float*)d_in[5];
    float* out = (float*)d_out;

    char* ws = (char*)d_ws;

    if (ws_size >= WS_NEW) {
        __half* Y     = (__half*)(ws + Y_OFF);
        int2*  binned = (int2*)(ws + BIN_OFF);
        int*   gcnt   = (int*) (ws + GCNT_OFF);
        int*   oc     = (int*) (ws + OC_OFF);
        int4*  ovf    = (int4*)(ws + OVF_OFF);

        zero_xw_kernel<<<ZB + NBM, 256, 0, stream>>>(X, W, Y, gcnt, oc);
        bin_kernel<<<BIN_BLOCKS, BIN_T, 0, stream>>>(esrc, edst, ew, gcnt, binned, oc, ovf);
        bucket_gather_kernel<<<NBKT, 512, 0, stream>>>(gcnt, binned, oc, ovf, Y, b, out);
    } else {
        float* Y = (float*)(ws + Y_OFF);
        xw_kernel<<<1024, 256, 0, stream>>>(X, W, Y);
        init_out_kernel<<<(V * (C / 4) + 255) / 256, 256, 0, stream>>>(b, (float4*)out);
        scatter_kernel<<<(E * 16 + 255) / 256, 256, 0, stream>>>(esrc, edst, ew, Y, out);
    }
}